// Round 4
// baseline (385.226 us; speedup 1.0000x reference)
//
#include <hip/hip_runtime.h>
#include <hip/hip_bf16.h>
#include <cstdint>
#include <cstddef>
#include <cstring>

#define B_ 2
#define T_ 2048
#define C_ 1024
#define H_ 16
#define HD_ 64
#define FF_ 4096
#define BT_ (B_*T_)   // 4096 rows

typedef __attribute__((ext_vector_type(8))) short short8;
typedef __attribute__((ext_vector_type(4))) float f32x4;

__device__ __forceinline__ ushort f2bf(float f) {
    uint x = __float_as_uint(f);
    return (ushort)((x + 0x7fffu + ((x >> 16) & 1u)) >> 16);
}
// hot-path convert: scalar cast so compiler can fuse v_cvt_pk_bf16_f32 (m240)
__device__ __forceinline__ ushort f2bf_hw(float f) {
    __hip_bfloat16 h = __float2bfloat16(f);
    ushort u;
    __builtin_memcpy(&u, &h, 2);
    return u;
}

#define GLDS16(g, l)                                                        \
    __builtin_amdgcn_global_load_lds(                                       \
        (const __attribute__((address_space(1))) void*)(g),                 \
        (__attribute__((address_space(3))) void*)(l), 16, 0, 0)

// ---------------------------------------------------------------------------
// LayerNorm: one block (256 threads) per row of C_=1024, fp32 in, bf16 out.
// ---------------------------------------------------------------------------
__global__ __launch_bounds__(256) void ln_kernel(const float* __restrict__ x,
                                                 const float* __restrict__ g,
                                                 const float* __restrict__ b,
                                                 ushort* __restrict__ out) {
    int row = blockIdx.x;
    int tid = threadIdx.x;
    const float* xr = x + (size_t)row * C_;
    float4 v = *(const float4*)(xr + tid * 4);
    float s = v.x + v.y + v.z + v.w;
    float q = v.x*v.x + v.y*v.y + v.z*v.z + v.w*v.w;
    #pragma unroll
    for (int off = 32; off > 0; off >>= 1) {
        s += __shfl_down(s, off);
        q += __shfl_down(q, off);
    }
    __shared__ float ss[4], qs[4];
    if ((tid & 63) == 0) { ss[tid >> 6] = s; qs[tid >> 6] = q; }
    __syncthreads();
    s = ss[0] + ss[1] + ss[2] + ss[3];
    q = qs[0] + qs[1] + qs[2] + qs[3];
    float mu  = s * (1.0f / C_);
    float var = q * (1.0f / C_) - mu * mu;
    float r = rsqrtf(var + 1e-5f);
    float4 gv = *(const float4*)(g + tid * 4);
    float4 bv = *(const float4*)(b + tid * 4);
    ushort4 o;
    o.x = f2bf((v.x - mu) * r * gv.x + bv.x);
    o.y = f2bf((v.y - mu) * r * gv.y + bv.y);
    o.z = f2bf((v.z - mu) * r * gv.z + bv.z);
    o.w = f2bf((v.w - mu) * r * gv.w + bv.w);
    *(ushort4*)(out + (size_t)row * C_ + tid * 4) = o;
}

// ---------------------------------------------------------------------------
// Tiled transpose + fp32->bf16 convert. (weights, once per call)
// ---------------------------------------------------------------------------
__global__ __launch_bounds__(256) void tcvt_kernel(const float* __restrict__ in,
                                                   ushort* __restrict__ out,
                                                   int R, int Cc, int ldo,
                                                   long in_bs, long out_bs) {
    __shared__ float tile[32][33];
    const float* inz = in + (size_t)blockIdx.z * in_bs;
    ushort* outz = out + (size_t)blockIdx.z * out_bs;
    int c0 = blockIdx.x * 32, r0 = blockIdx.y * 32;
    #pragma unroll
    for (int i = 0; i < 4; i++) {
        int r = threadIdx.y + i * 8;
        tile[r][threadIdx.x] = inz[(size_t)(r0 + r) * Cc + c0 + threadIdx.x];
    }
    __syncthreads();
    #pragma unroll
    for (int i = 0; i < 4; i++) {
        int c = threadIdx.y + i * 8;
        outz[(size_t)(c0 + c) * ldo + r0 + threadIdx.x] = f2bf(tile[threadIdx.x][c]);
    }
}

// ---------------------------------------------------------------------------
// bf16 MFMA GEMM (m97 structure): 128x128 tile, BK=32, 4 waves.
// A [M][K] bf16, Bt [N][K] bf16. EPI: 1=bias, 2=relu, 4=residual fp32.
// ---------------------------------------------------------------------------
template<int EPI, bool OUT_BF16>
__global__ __launch_bounds__(256) void gemm_bf16(
    const ushort* __restrict__ A,
    const ushort* __restrict__ Bt,
    void* __restrict__ Cout,
    const float* __restrict__ bias,
    const float* __restrict__ resid,
    int M, int N, int K)
{
    __shared__ ushort As[128 * 32];
    __shared__ ushort Bs[128 * 32];

    int tid  = threadIdx.x;
    int lane = tid & 63;
    int lr = lane & 15, lq = lane >> 4;
    int wave = tid >> 6;
    int wr = wave >> 1, wc = wave & 1;
    int m0 = blockIdx.y * 128, n0 = blockIdx.x * 128;

    f32x4 acc[4][4];
    #pragma unroll
    for (int m = 0; m < 4; m++)
        #pragma unroll
        for (int n = 0; n < 4; n++)
            acc[m][n] = {0.f, 0.f, 0.f, 0.f};

    int arow = tid >> 2;
    int acol = (tid & 3) * 8;
    const ushort* ga = A  + (size_t)(m0 + arow) * K + acol;
    const ushort* gb = Bt + (size_t)(n0 + arow) * K + acol;
    int lbase = wave * 1024;

    for (int k0 = 0; k0 < K; k0 += 32) {
        GLDS16(ga + k0,                (char*)As + lbase);
        GLDS16(ga + 64*(size_t)K + k0, (char*)As + 4096 + lbase);
        GLDS16(gb + k0,                (char*)Bs + lbase);
        GLDS16(gb + 64*(size_t)K + k0, (char*)Bs + 4096 + lbase);
        __syncthreads();

        short8 a[4], b[4];
        #pragma unroll
        for (int m = 0; m < 4; m++)
            a[m] = *(const short8*)(As + (wr*64 + m*16 + lr) * 32 + lq*8);
        #pragma unroll
        for (int n = 0; n < 4; n++)
            b[n] = *(const short8*)(Bs + (wc*64 + n*16 + lr) * 32 + lq*8);
        #pragma unroll
        for (int m = 0; m < 4; m++)
            #pragma unroll
            for (int n = 0; n < 4; n++)
                acc[m][n] = __builtin_amdgcn_mfma_f32_16x16x32_bf16(
                    a[m], b[n], acc[m][n], 0, 0, 0);
        __syncthreads();
    }

    #pragma unroll
    for (int m = 0; m < 4; m++) {
        #pragma unroll
        for (int n = 0; n < 4; n++) {
            int col = n0 + wc*64 + n*16 + lr;
            #pragma unroll
            for (int j = 0; j < 4; j++) {
                int row = m0 + wr*64 + m*16 + lq*4 + j;
                float v = acc[m][n][j];
                if (EPI & 1) v += bias[col];
                if (EPI & 2) v = fmaxf(v, 0.f);
                if (EPI & 4) v += resid[(size_t)row * N + col];
                if (OUT_BF16)
                    ((ushort*)Cout)[(size_t)row * N + col] = f2bf(v);
                else
                    ((float*)Cout)[(size_t)row * N + col] = v;
            }
        }
    }
}

// ---------------------------------------------------------------------------
// MFMA causal flash attention, KVBLK=128.
// qk : [BT_][2048] bf16 (q at h*64, k at 1024+h*64)
// vt : [1024][4096] bf16 = V^T, row = h*64+d, col = bb*2048+s
// out: [BT_][1024] bf16
// 4 waves; wave w owns q rows qw..qw+31 (2 fragment rows). Per 128-key tile:
// S=QK^T (16 MFMA/wave), log2-domain online softmax with defer-max (T13),
// row-sums via MFMA-ones, P bf16 -> per-wave swizzled LDS, O+=PV (32 MFMA).
// ---------------------------------------------------------------------------
__global__ __launch_bounds__(256) void attn_mfma(const ushort* __restrict__ qk,
                                                 const ushort* __restrict__ vt,
                                                 ushort* __restrict__ attn_out) {
    const float C2 = 0.18033688011f;     // 0.125 * log2(e)
    const float THR2 = 12.0f;            // defer-max threshold (log2 domain)

    int bh = blockIdx.y;
    int bb = bh >> 4;
    int head = bh & 15;
    int qa = 15 - blockIdx.x;            // heavy tiles first
    int q0 = qa * 128;

    int tid  = threadIdx.x;
    int lane = tid & 63;
    int lr = lane & 15, lq = lane >> 4;
    int wave = tid >> 6;
    int qw = q0 + wave * 32;

    __shared__ ushort Ks[128 * 64];      // 16KB [key][d], swizzled 16B slots
    __shared__ ushort Vs[64 * 128];      // 16KB [d][key], swizzled
    __shared__ ushort Ps[4][32 * 128];   // 32KB per-wave P [q][k], swizzled

    // Q fragments (held in registers the whole kernel)
    short8 qf[2][2];
    {
        const ushort* qb = qk + ((size_t)(bb * T_ + qw)) * 2048 + head * 64;
        #pragma unroll
        for (int mt = 0; mt < 2; mt++)
            #pragma unroll
            for (int kk = 0; kk < 2; kk++)
                qf[mt][kk] = *(const short8*)(qb + (size_t)(mt*16 + lr) * 2048 + kk*32 + lq*8);
    }

    f32x4 acc[2][4];
    f32x4 lsum[2];
    float m2[2][4];
    #pragma unroll
    for (int mt = 0; mt < 2; mt++) {
        #pragma unroll
        for (int dt = 0; dt < 4; dt++) acc[mt][dt] = {0.f, 0.f, 0.f, 0.f};
        lsum[mt] = {0.f, 0.f, 0.f, 0.f};
        #pragma unroll
        for (int j = 0; j < 4; j++) m2[mt][j] = -INFINITY;
    }

    const short8 onesf = {(short)0x3F80, (short)0x3F80, (short)0x3F80, (short)0x3F80,
                          (short)0x3F80, (short)0x3F80, (short)0x3F80, (short)0x3F80};

    // staging geometry (pre-swizzled global source, linear LDS dest)
    int krow = tid >> 3;                       // 0..31
    int ksc = ((tid & 7) ^ (krow & 7)) * 8;
    const ushort* kg0 = qk + ((size_t)(bb * T_ + krow)) * 2048 + 1024 + head * 64 + ksc;
    int vrow = tid >> 4;                       // 0..15
    int vsc = ((tid & 15) ^ (vrow & 7)) * 8;
    const ushort* vg0 = vt + ((size_t)(head * 64 + vrow)) * 4096 + (size_t)bb * 2048 + vsc;

    int nt = qa + 1;
    for (int it = 0; it < nt; it++) {
        int s0 = it * 128;
        __syncthreads();   // prior tile's LDS reads complete
        #pragma unroll
        for (int i = 0; i < 4; i++)
            GLDS16(kg0 + (size_t)(s0 + i*32) * 2048, (char*)Ks + i*4096 + wave*1024);
        #pragma unroll
        for (int i = 0; i < 4; i++)
            GLDS16(vg0 + (size_t)(i*16) * 4096 + s0, (char*)Vs + i*4096 + wave*1024);
        __syncthreads();   // drains vmcnt: tiles visible

        // ---- S = Q K^T ----
        f32x4 sa[2][8];
        __builtin_amdgcn_s_setprio(1);
        #pragma unroll
        for (int n = 0; n < 8; n++) {
            int row = n*16 + lr;
            const char* kbase = (const char*)Ks + row*128;
            short8 kf0 = *(const short8*)(kbase + ((lq       ^ (row & 7)) << 4));
            short8 kf1 = *(const short8*)(kbase + (((4 + lq) ^ (row & 7)) << 4));
            #pragma unroll
            for (int mt = 0; mt < 2; mt++) {
                f32x4 t = {0.f, 0.f, 0.f, 0.f};
                t = __builtin_amdgcn_mfma_f32_16x16x32_bf16(qf[mt][0], kf0, t, 0, 0, 0);
                t = __builtin_amdgcn_mfma_f32_16x16x32_bf16(qf[mt][1], kf1, t, 0, 0, 0);
                sa[mt][n] = t;
            }
        }
        __builtin_amdgcn_s_setprio(0);

        // ---- causal mask (diagonal tile only; wave-uniform branch) ----
        if (s0 + 127 > qw) {
            #pragma unroll
            for (int mt = 0; mt < 2; mt++)
                #pragma unroll
                for (int n = 0; n < 8; n++)
                    #pragma unroll
                    for (int j = 0; j < 4; j++) {
                        int scol = s0 + n*16 + lr;
                        int qrow = qw + mt*16 + lq*4 + j;
                        if (scol > qrow) sa[mt][n][j] = -INFINITY;
                    }
        }

        // ---- row maxes (log2-scaled) + defer-max vote ----
        float vmax2[2][4];
        bool grow = false;
        #pragma unroll
        for (int mt = 0; mt < 2; mt++) {
            #pragma unroll
            for (int j = 0; j < 4; j++) {
                float a0 = fmaxf(sa[mt][0][j], sa[mt][1][j]);
                float a1 = fmaxf(sa[mt][2][j], sa[mt][3][j]);
                float a2 = fmaxf(sa[mt][4][j], sa[mt][5][j]);
                float a3 = fmaxf(sa[mt][6][j], sa[mt][7][j]);
                float v = fmaxf(fmaxf(a0, a1), fmaxf(a2, a3));
                #pragma unroll
                for (int off = 1; off < 16; off <<= 1)
                    v = fmaxf(v, __shfl_xor(v, off));
                float v2 = v * C2;
                vmax2[mt][j] = v2;
                grow |= (v2 > m2[mt][j] + THR2);
            }
        }
        if (__any(grow)) {
            #pragma unroll
            for (int mt = 0; mt < 2; mt++)
                #pragma unroll
                for (int j = 0; j < 4; j++) {
                    float m2n = fmaxf(m2[mt][j], vmax2[mt][j]);
                    float corr = __builtin_amdgcn_exp2f(m2[mt][j] - m2n);
                    m2[mt][j] = m2n;
                    lsum[mt][j] *= corr;
                    #pragma unroll
                    for (int dt = 0; dt < 4; dt++)
                        acc[mt][dt][j] *= corr;
                }
        }

        // ---- P = exp2(s*C2 - m2) -> bf16 -> per-wave swizzled LDS ----
        char* pw = (char*)Ps[wave];
        #pragma unroll
        for (int mt = 0; mt < 2; mt++)
            #pragma unroll
            for (int n = 0; n < 8; n++)
                #pragma unroll
                for (int j = 0; j < 4; j++) {
                    float p = __builtin_amdgcn_exp2f(
                        fmaf(sa[mt][n][j], C2, -m2[mt][j]));
                    int row = mt*16 + lq*4 + j;
                    int col = n*16 + lr;
                    int byte = row*256 + ((((col >> 3) ^ (row & 7))) << 4) + (col & 7)*2;
                    *(ushort*)(pw + byte) = f2bf_hw(p);
                }

        // ---- read P fragments; lsum += P*1; O += P V ----
        short8 pf[2][4];
        #pragma unroll
        for (int mt = 0; mt < 2; mt++) {
            int row = mt*16 + lr;
            #pragma unroll
            for (int kk = 0; kk < 4; kk++)
                pf[mt][kk] = *(const short8*)(pw + row*256
                               + (((kk*4 + lq) ^ (row & 7)) << 4));
        }
        __builtin_amdgcn_s_setprio(1);
        #pragma unroll
        for (int kk = 0; kk < 4; kk++)
            #pragma unroll
            for (int mt = 0; mt < 2; mt++)
                lsum[mt] = __builtin_amdgcn_mfma_f32_16x16x32_bf16(
                    pf[mt][kk], onesf, lsum[mt], 0, 0, 0);
        #pragma unroll
        for (int dt = 0; dt < 4; dt++) {
            int row = dt*16 + lr;
            const char* vbase = (const char*)Vs + row*256;
            #pragma unroll
            for (int kk = 0; kk < 4; kk++) {
                short8 vf = *(const short8*)(vbase + (((kk*4 + lq) ^ (row & 7)) << 4));
                #pragma unroll
                for (int mt = 0; mt < 2; mt++)
                    acc[mt][dt] = __builtin_amdgcn_mfma_f32_16x16x32_bf16(
                        pf[mt][kk], vf, acc[mt][dt], 0, 0, 0);
            }
        }
        __builtin_amdgcn_s_setprio(0);
    }

    // ---- epilogue: O / lsum ----
    ushort* ob = attn_out + ((size_t)(bb * T_ + qw)) * 1024 + head * 64;
    #pragma unroll
    for (int mt = 0; mt < 2; mt++)
        #pragma unroll
        for (int j = 0; j < 4; j++) {
            float inv = 1.0f / lsum[mt][j];
            #pragma unroll
            for (int dt = 0; dt < 4; dt++)
                ob[(size_t)(mt*16 + lq*4 + j) * 1024 + dt*16 + lr] =
                    f2bf(acc[mt][dt][j] * inv);
        }
}

// ---------------------------------------------------------------------------
extern "C" void kernel_launch(void* const* d_in, const int* in_sizes, int n_in,
                              void* d_out, int out_size, void* d_ws, size_t ws_size,
                              hipStream_t stream) {
    const float* x   = (const float*)d_in[0];
    const float* Wq  = (const float*)d_in[1];
    const float* Wk  = (const float*)d_in[2];
    const float* Wv  = (const float*)d_in[3];
    const float* Wo  = (const float*)d_in[4];
    const float* bo  = (const float*)d_in[5];
    const float* W1  = (const float*)d_in[6];
    const float* b1  = (const float*)d_in[7];
    const float* W2  = (const float*)d_in[8];
    const float* b2  = (const float*)d_in[9];
    const float* g1  = (const float*)d_in[10];
    const float* be1 = (const float*)d_in[11];
    const float* g2  = (const float*)d_in[12];
    const float* be2 = (const float*)d_in[13];
    float* out = (float*)d_out;

    char* ws = (char*)d_ws;
    const size_t MB = 1 << 20;
    ushort* h_bf    = (ushort*)(ws);                 // 8 MB
    ushort* qk_act  = (ushort*)(ws + 8*MB);          // 16 MB [4096][2048]
    ushort* vt      = (ushort*)(ws + 24*MB);         // 8 MB  [1024][4096] V^T
    ushort* attn_bf = (ushort*)(ws + 32*MB);         // 8 MB  [4096][1024]
    ushort* ff1     = (ushort*)(ws + 8*MB);          // 32 MB (reuses qk/vt/attn)
    ushort* qkvw    = (ushort*)(ws + 40*MB);         // 6 MB  [3072][1024]
    ushort* Wo_t    = (ushort*)(ws + 46*MB);         // 2 MB
    ushort* W1_t    = (ushort*)(ws + 48*MB);         // 8 MB
    ushort* W2_t    = (ushort*)(ws + 56*MB);         // 8 MB

    // --- weight transposes + bf16 convert ---
    const float* Wsrc[3] = {Wq, Wk, Wv};
    for (int w = 0; w < 3; w++) {
        tcvt_kernel<<<dim3(2, 32, 16), dim3(32, 8), 0, stream>>>(
            Wsrc[w], qkvw + (size_t)w * 1024 * 1024,
            1024, 64, 1024, 65536L, 65536L);
    }
    tcvt_kernel<<<dim3(32, 32, 1), dim3(32, 8), 0, stream>>>(
        Wo, Wo_t, 1024, 1024, 1024, 0L, 0L);
    tcvt_kernel<<<dim3(128, 32, 1), dim3(32, 8), 0, stream>>>(
        W1, W1_t, 1024, 4096, 1024, 0L, 0L);
    tcvt_kernel<<<dim3(32, 128, 1), dim3(32, 8), 0, stream>>>(
        W2, W2_t, 4096, 1024, 4096, 0L, 0L);

    // 1) h = LN(x) -> bf16
    ln_kernel<<<dim3(BT_), dim3(256), 0, stream>>>(x, g1, be1, h_bf);

    // 2a) qk = h @ [Wq|Wk]^T   [4096][2048]
    gemm_bf16<0, true><<<dim3(2048/128, BT_/128), dim3(256), 0, stream>>>(
        h_bf, qkvw, qk_act, nullptr, nullptr, BT_, 2048, C_);
    // 2b) vt = Wv^T-rows @ h^T  -> V^T [1024][4096]  (swapped operands)
    gemm_bf16<0, true><<<dim3(BT_/128, 1024/128), dim3(256), 0, stream>>>(
        qkvw + (size_t)2*1024*1024, h_bf, vt, nullptr, nullptr, 1024, BT_, C_);

    // 3) attention (MFMA flash, KVBLK=128)
    attn_mfma<<<dim3(16, B_*H_), dim3(256), 0, stream>>>(qk_act, vt, attn_bf);

    // 4) out = x + attn @ Wo + bo   (fp32 out)
    gemm_bf16<1|4, false><<<dim3(1024/128, BT_/128), dim3(256), 0, stream>>>(
        attn_bf, Wo_t, out, bo, x, BT_, C_, C_);

    // 5) h2 = LN(out) -> bf16
    ln_kernel<<<dim3(BT_), dim3(256), 0, stream>>>(out, g2, be2, h_bf);

    // 6) ff1 = relu(h2 @ W1 + b1) -> bf16
    gemm_bf16<1|2, true><<<dim3(4096/128, BT_/128), dim3(256), 0, stream>>>(
        h_bf, W1_t, ff1, b1, nullptr, BT_, FF_, C_);

    // 7) out = out + ff1 @ W2 + b2  (fp32, residual = out itself)
    gemm_bf16<1|4, false><<<dim3(1024/128, BT_/128), dim3(256), 0, stream>>>(
        ff1, W2_t, out, b2, out, BT_, C_, FF_);
}

// Round 5
// 354.392 us; speedup vs baseline: 1.0870x; 1.0870x over previous
//
#include <hip/hip_runtime.h>
#include <hip/hip_bf16.h>
#include <cstdint>
#include <cstddef>
#include <cstring>

#define B_ 2
#define T_ 2048
#define C_ 1024
#define H_ 16
#define HD_ 64
#define FF_ 4096
#define BT_ (B_*T_)   // 4096 rows

typedef __attribute__((ext_vector_type(8))) short short8;
typedef __attribute__((ext_vector_type(4))) float f32x4;

__device__ __forceinline__ ushort f2bf(float f) {
    uint x = __float_as_uint(f);
    return (ushort)((x + 0x7fffu + ((x >> 16) & 1u)) >> 16);
}
// hot-path convert: scalar cast so compiler can fuse v_cvt_pk_bf16_f32 (m240)
__device__ __forceinline__ ushort f2bf_hw(float f) {
    __hip_bfloat16 h = __float2bfloat16(f);
    ushort u;
    __builtin_memcpy(&u, &h, 2);
    return u;
}

#define GLDS16(g, l)                                                        \
    __builtin_amdgcn_global_load_lds(                                       \
        (const __attribute__((address_space(1))) void*)(g),                 \
        (__attribute__((address_space(3))) void*)(l), 16, 0, 0)

// ---------------------------------------------------------------------------
// LayerNorm: one block (256 threads) per row of C_=1024, fp32 in, bf16 out.
// ---------------------------------------------------------------------------
__global__ __launch_bounds__(256) void ln_kernel(const float* __restrict__ x,
                                                 const float* __restrict__ g,
                                                 const float* __restrict__ b,
                                                 ushort* __restrict__ out) {
    int row = blockIdx.x;
    int tid = threadIdx.x;
    const float* xr = x + (size_t)row * C_;
    float4 v = *(const float4*)(xr + tid * 4);
    float s = v.x + v.y + v.z + v.w;
    float q = v.x*v.x + v.y*v.y + v.z*v.z + v.w*v.w;
    #pragma unroll
    for (int off = 32; off > 0; off >>= 1) {
        s += __shfl_down(s, off);
        q += __shfl_down(q, off);
    }
    __shared__ float ss[4], qs[4];
    if ((tid & 63) == 0) { ss[tid >> 6] = s; qs[tid >> 6] = q; }
    __syncthreads();
    s = ss[0] + ss[1] + ss[2] + ss[3];
    q = qs[0] + qs[1] + qs[2] + qs[3];
    float mu  = s * (1.0f / C_);
    float var = q * (1.0f / C_) - mu * mu;
    float r = rsqrtf(var + 1e-5f);
    float4 gv = *(const float4*)(g + tid * 4);
    float4 bv = *(const float4*)(b + tid * 4);
    ushort4 o;
    o.x = f2bf((v.x - mu) * r * gv.x + bv.x);
    o.y = f2bf((v.y - mu) * r * gv.y + bv.y);
    o.z = f2bf((v.z - mu) * r * gv.z + bv.z);
    o.w = f2bf((v.w - mu) * r * gv.w + bv.w);
    *(ushort4*)(out + (size_t)row * C_ + tid * 4) = o;
}

// ---------------------------------------------------------------------------
// Tiled transpose + fp32->bf16 convert. (weights, once per call)
// ---------------------------------------------------------------------------
__global__ __launch_bounds__(256) void tcvt_kernel(const float* __restrict__ in,
                                                   ushort* __restrict__ out,
                                                   int R, int Cc, int ldo,
                                                   long in_bs, long out_bs) {
    __shared__ float tile[32][33];
    const float* inz = in + (size_t)blockIdx.z * in_bs;
    ushort* outz = out + (size_t)blockIdx.z * out_bs;
    int c0 = blockIdx.x * 32, r0 = blockIdx.y * 32;
    #pragma unroll
    for (int i = 0; i < 4; i++) {
        int r = threadIdx.y + i * 8;
        tile[r][threadIdx.x] = inz[(size_t)(r0 + r) * Cc + c0 + threadIdx.x];
    }
    __syncthreads();
    #pragma unroll
    for (int i = 0; i < 4; i++) {
        int c = threadIdx.y + i * 8;
        outz[(size_t)(c0 + c) * ldo + r0 + threadIdx.x] = f2bf(tile[threadIdx.x][c]);
    }
}

// ---------------------------------------------------------------------------
// bf16 MFMA GEMM (m97 structure): 128x128 tile, BK=32, 4 waves.
// A [M][K] bf16, Bt [N][K] bf16. EPI: 1=bias, 2=relu, 4=residual fp32.
// ---------------------------------------------------------------------------
template<int EPI, bool OUT_BF16>
__global__ __launch_bounds__(256) void gemm_bf16(
    const ushort* __restrict__ A,
    const ushort* __restrict__ Bt,
    void* __restrict__ Cout,
    const float* __restrict__ bias,
    const float* __restrict__ resid,
    int M, int N, int K)
{
    __shared__ ushort As[128 * 32];
    __shared__ ushort Bs[128 * 32];

    int tid  = threadIdx.x;
    int lane = tid & 63;
    int lr = lane & 15, lq = lane >> 4;
    int wave = tid >> 6;
    int wr = wave >> 1, wc = wave & 1;
    int m0 = blockIdx.y * 128, n0 = blockIdx.x * 128;

    f32x4 acc[4][4];
    #pragma unroll
    for (int m = 0; m < 4; m++)
        #pragma unroll
        for (int n = 0; n < 4; n++)
            acc[m][n] = {0.f, 0.f, 0.f, 0.f};

    int arow = tid >> 2;
    int acol = (tid & 3) * 8;
    const ushort* ga = A  + (size_t)(m0 + arow) * K + acol;
    const ushort* gb = Bt + (size_t)(n0 + arow) * K + acol;
    int lbase = wave * 1024;

    for (int k0 = 0; k0 < K; k0 += 32) {
        GLDS16(ga + k0,                (char*)As + lbase);
        GLDS16(ga + 64*(size_t)K + k0, (char*)As + 4096 + lbase);
        GLDS16(gb + k0,                (char*)Bs + lbase);
        GLDS16(gb + 64*(size_t)K + k0, (char*)Bs + 4096 + lbase);
        __syncthreads();

        short8 a[4], b[4];
        #pragma unroll
        for (int m = 0; m < 4; m++)
            a[m] = *(const short8*)(As + (wr*64 + m*16 + lr) * 32 + lq*8);
        #pragma unroll
        for (int n = 0; n < 4; n++)
            b[n] = *(const short8*)(Bs + (wc*64 + n*16 + lr) * 32 + lq*8);
        #pragma unroll
        for (int m = 0; m < 4; m++)
            #pragma unroll
            for (int n = 0; n < 4; n++)
                acc[m][n] = __builtin_amdgcn_mfma_f32_16x16x32_bf16(
                    a[m], b[n], acc[m][n], 0, 0, 0);
        __syncthreads();
    }

    #pragma unroll
    for (int m = 0; m < 4; m++) {
        #pragma unroll
        for (int n = 0; n < 4; n++) {
            int col = n0 + wc*64 + n*16 + lr;
            #pragma unroll
            for (int j = 0; j < 4; j++) {
                int row = m0 + wr*64 + m*16 + lq*4 + j;
                float v = acc[m][n][j];
                if (EPI & 1) v += bias[col];
                if (EPI & 2) v = fmaxf(v, 0.f);
                if (EPI & 4) v += resid[(size_t)row * N + col];
                if (OUT_BF16)
                    ((ushort*)Cout)[(size_t)row * N + col] = f2bf(v);
                else
                    ((float*)Cout)[(size_t)row * N + col] = v;
            }
        }
    }
}

// ---------------------------------------------------------------------------
// MFMA causal flash attention, KVBLK=128 staged, processed in 64-key halves.
// Double-buffered K/V with prefetch: stage(it+1) issued BEFORE compute(it),
// single barrier per tile -> load latency hides under compute (T3 2-phase).
// qk : [BT_][2048] bf16 (q at h*64, k at 1024+h*64)
// vt : [1024][4096] bf16 = V^T, row = h*64+d, col = bb*2048+s
// out: [BT_][1024] bf16
// ---------------------------------------------------------------------------
__global__ __launch_bounds__(256) void attn_mfma(const ushort* __restrict__ qk,
                                                 const ushort* __restrict__ vt,
                                                 ushort* __restrict__ attn_out) {
    const float C2 = 0.18033688011f;     // 0.125 * log2(e)
    const float THR2 = 12.0f;            // defer-max threshold (log2 domain)

    int bh = blockIdx.y;
    int bb = bh >> 4;
    int head = bh & 15;
    int qa = 15 - blockIdx.x;            // heavy tiles first
    int q0 = qa * 128;

    int tid  = threadIdx.x;
    int lane = tid & 63;
    int lr = lane & 15, lq = lane >> 4;
    int wave = tid >> 6;
    int qw = q0 + wave * 32;

    __shared__ ushort Ks[2][128 * 64];   // 2 x 16KB [key][d], swizzled slots
    __shared__ ushort Vs[2][64 * 128];   // 2 x 16KB [d][key], swizzled
    __shared__ ushort Ps[4][32 * 64];    // 16KB per-wave P [q][k64], swizzled

    // Q fragments (held in registers the whole kernel)
    short8 qf[2][2];
    {
        const ushort* qb = qk + ((size_t)(bb * T_ + qw)) * 2048 + head * 64;
        #pragma unroll
        for (int mt = 0; mt < 2; mt++)
            #pragma unroll
            for (int kk = 0; kk < 2; kk++)
                qf[mt][kk] = *(const short8*)(qb + (size_t)(mt*16 + lr) * 2048 + kk*32 + lq*8);
    }

    f32x4 acc[2][4];
    f32x4 lsum[2];
    float m2[2][4];
    #pragma unroll
    for (int mt = 0; mt < 2; mt++) {
        #pragma unroll
        for (int dt = 0; dt < 4; dt++) acc[mt][dt] = {0.f, 0.f, 0.f, 0.f};
        lsum[mt] = {0.f, 0.f, 0.f, 0.f};
        #pragma unroll
        for (int j = 0; j < 4; j++) m2[mt][j] = -INFINITY;
    }

    const short8 onesf = {(short)0x3F80, (short)0x3F80, (short)0x3F80, (short)0x3F80,
                          (short)0x3F80, (short)0x3F80, (short)0x3F80, (short)0x3F80};

    // staging geometry (pre-swizzled global source, linear LDS dest)
    int krow = tid >> 3;                       // 0..31
    int ksc = ((tid & 7) ^ (krow & 7)) * 8;
    const ushort* kg0 = qk + ((size_t)(bb * T_ + krow)) * 2048 + 1024 + head * 64 + ksc;
    int vrow = tid >> 4;                       // 0..15
    int vsc = ((tid & 15) ^ (vrow & 7)) * 8;
    const ushort* vg0 = vt + ((size_t)(head * 64 + vrow)) * 4096 + (size_t)bb * 2048 + vsc;

    auto stage = [&](int it, int buf) {
        int s0 = it * 128;
        char* Kb = (char*)Ks[buf] + wave * 1024;
        char* Vb = (char*)Vs[buf] + wave * 1024;
        #pragma unroll
        for (int i = 0; i < 4; i++)
            GLDS16(kg0 + (size_t)(s0 + i*32) * 2048, Kb + i*4096);
        #pragma unroll
        for (int i = 0; i < 4; i++)
            GLDS16(vg0 + (size_t)(i*16) * 4096 + s0, Vb + i*4096);
    };

    int nt = qa + 1;
    stage(0, 0);
    __syncthreads();                      // drain: tile 0 visible
    int cur = 0;

    for (int it = 0; it < nt; it++) {
        if (it + 1 < nt) stage(it + 1, cur ^ 1);   // prefetch under compute

        const ushort* Kc = Ks[cur];
        const ushort* Vc = Vs[cur];
        #pragma unroll
        for (int h = 0; h < 2; h++) {
            int s0h = it * 128 + h * 64;
            if (s0h > qw + 31) continue;           // wave-uniform causal skip

            // ---- S = Q K^T (64 keys) ----
            f32x4 sa[2][4];
            __builtin_amdgcn_s_setprio(1);
            #pragma unroll
            for (int n = 0; n < 4; n++) {
                int row = h*64 + n*16 + lr;
                const char* kbase = (const char*)Kc + row*128;
                short8 kf0 = *(const short8*)(kbase + ((lq       ^ (row & 7)) << 4));
                short8 kf1 = *(const short8*)(kbase + (((4 + lq) ^ (row & 7)) << 4));
                #pragma unroll
                for (int mt = 0; mt < 2; mt++) {
                    f32x4 t = {0.f, 0.f, 0.f, 0.f};
                    t = __builtin_amdgcn_mfma_f32_16x16x32_bf16(qf[mt][0], kf0, t, 0, 0, 0);
                    t = __builtin_amdgcn_mfma_f32_16x16x32_bf16(qf[mt][1], kf1, t, 0, 0, 0);
                    sa[mt][n] = t;
                }
            }
            __builtin_amdgcn_s_setprio(0);

            // ---- causal mask (diagonal half only; wave-uniform branch) ----
            if (s0h + 63 > qw) {
                #pragma unroll
                for (int mt = 0; mt < 2; mt++)
                    #pragma unroll
                    for (int n = 0; n < 4; n++)
                        #pragma unroll
                        for (int j = 0; j < 4; j++) {
                            int scol = s0h + n*16 + lr;
                            int qrow = qw + mt*16 + lq*4 + j;
                            if (scol > qrow) sa[mt][n][j] = -INFINITY;
                        }
            }

            // ---- row maxes (log2-scaled) + defer-max vote ----
            float vmax2[2][4];
            bool grow = false;
            #pragma unroll
            for (int mt = 0; mt < 2; mt++) {
                #pragma unroll
                for (int j = 0; j < 4; j++) {
                    float v = fmaxf(fmaxf(sa[mt][0][j], sa[mt][1][j]),
                                    fmaxf(sa[mt][2][j], sa[mt][3][j]));
                    #pragma unroll
                    for (int off = 1; off < 16; off <<= 1)
                        v = fmaxf(v, __shfl_xor(v, off));
                    float v2 = v * C2;
                    vmax2[mt][j] = v2;
                    grow |= (v2 > m2[mt][j] + THR2);
                }
            }
            if (__any(grow)) {
                #pragma unroll
                for (int mt = 0; mt < 2; mt++)
                    #pragma unroll
                    for (int j = 0; j < 4; j++) {
                        float m2n = fmaxf(m2[mt][j], vmax2[mt][j]);
                        float corr = __builtin_amdgcn_exp2f(m2[mt][j] - m2n);
                        m2[mt][j] = m2n;
                        lsum[mt][j] *= corr;
                        #pragma unroll
                        for (int dt = 0; dt < 4; dt++)
                            acc[mt][dt][j] *= corr;
                    }
            }

            // ---- P = exp2(s*C2 - m2) -> bf16 -> per-wave swizzled LDS ----
            char* pw = (char*)Ps[wave];
            #pragma unroll
            for (int mt = 0; mt < 2; mt++)
                #pragma unroll
                for (int n = 0; n < 4; n++)
                    #pragma unroll
                    for (int j = 0; j < 4; j++) {
                        float p = __builtin_amdgcn_exp2f(
                            fmaf(sa[mt][n][j], C2, -m2[mt][j]));
                        int row = mt*16 + lq*4 + j;
                        int col = n*16 + lr;
                        int byte = row*128 + ((((col >> 3) ^ (row & 7))) << 4) + (col & 7)*2;
                        *(ushort*)(pw + byte) = f2bf_hw(p);
                    }

            // ---- read P fragments; lsum += P*1; O += P V ----
            short8 pf[2][2];
            #pragma unroll
            for (int mt = 0; mt < 2; mt++) {
                int row = mt*16 + lr;
                #pragma unroll
                for (int kk = 0; kk < 2; kk++)
                    pf[mt][kk] = *(const short8*)(pw + row*128
                                   + (((kk*4 + lq) ^ (row & 7)) << 4));
            }
            __builtin_amdgcn_s_setprio(1);
            #pragma unroll
            for (int kk = 0; kk < 2; kk++)
                #pragma unroll
                for (int mt = 0; mt < 2; mt++)
                    lsum[mt] = __builtin_amdgcn_mfma_f32_16x16x32_bf16(
                        pf[mt][kk], onesf, lsum[mt], 0, 0, 0);
            #pragma unroll
            for (int dt = 0; dt < 4; dt++) {
                int row = dt*16 + lr;
                const char* vbase = (const char*)Vc + row*256;
                #pragma unroll
                for (int kk = 0; kk < 2; kk++) {
                    short8 vf = *(const short8*)(vbase
                                  + ((((h*2 + kk)*4 + lq) ^ (row & 7)) << 4));
                    #pragma unroll
                    for (int mt = 0; mt < 2; mt++)
                        acc[mt][dt] = __builtin_amdgcn_mfma_f32_16x16x32_bf16(
                            pf[mt][kk], vf, acc[mt][dt], 0, 0, 0);
                }
            }
            __builtin_amdgcn_s_setprio(0);
        }

        __syncthreads();   // all waves done with buf[cur]; prefetched loads drained
        cur ^= 1;
    }

    // ---- epilogue: O / lsum ----
    ushort* ob = attn_out + ((size_t)(bb * T_ + qw)) * 1024 + head * 64;
    #pragma unroll
    for (int mt = 0; mt < 2; mt++)
        #pragma unroll
        for (int j = 0; j < 4; j++) {
            float inv = 1.0f / lsum[mt][j];
            #pragma unroll
            for (int dt = 0; dt < 4; dt++)
                ob[(size_t)(mt*16 + lq*4 + j) * 1024 + dt*16 + lr] =
                    f2bf(acc[mt][dt][j] * inv);
        }
}

// ---------------------------------------------------------------------------
extern "C" void kernel_launch(void* const* d_in, const int* in_sizes, int n_in,
                              void* d_out, int out_size, void* d_ws, size_t ws_size,
                              hipStream_t stream) {
    const float* x   = (const float*)d_in[0];
    const float* Wq  = (const float*)d_in[1];
    const float* Wk  = (const float*)d_in[2];
    const float* Wv  = (const float*)d_in[3];
    const float* Wo  = (const float*)d_in[4];
    const float* bo  = (const float*)d_in[5];
    const float* W1  = (const float*)d_in[6];
    const float* b1  = (const float*)d_in[7];
    const float* W2  = (const float*)d_in[8];
    const float* b2  = (const float*)d_in[9];
    const float* g1  = (const float*)d_in[10];
    const float* be1 = (const float*)d_in[11];
    const float* g2  = (const float*)d_in[12];
    const float* be2 = (const float*)d_in[13];
    float* out = (float*)d_out;

    char* ws = (char*)d_ws;
    const size_t MB = 1 << 20;
    ushort* h_bf    = (ushort*)(ws);                 // 8 MB
    ushort* qk_act  = (ushort*)(ws + 8*MB);          // 16 MB [4096][2048]
    ushort* vt      = (ushort*)(ws + 24*MB);         // 8 MB  [1024][4096] V^T
    ushort* attn_bf = (ushort*)(ws + 32*MB);         // 8 MB  [4096][1024]
    ushort* ff1     = (ushort*)(ws + 8*MB);          // 32 MB (reuses qk/vt/attn)
    ushort* qkvw    = (ushort*)(ws + 40*MB);         // 6 MB  [3072][1024]
    ushort* Wo_t    = (ushort*)(ws + 46*MB);         // 2 MB
    ushort* W1_t    = (ushort*)(ws + 48*MB);         // 8 MB
    ushort* W2_t    = (ushort*)(ws + 56*MB);         // 8 MB

    // --- weight transposes + bf16 convert ---
    const float* Wsrc[3] = {Wq, Wk, Wv};
    for (int w = 0; w < 3; w++) {
        tcvt_kernel<<<dim3(2, 32, 16), dim3(32, 8), 0, stream>>>(
            Wsrc[w], qkvw + (size_t)w * 1024 * 1024,
            1024, 64, 1024, 65536L, 65536L);
    }
    tcvt_kernel<<<dim3(32, 32, 1), dim3(32, 8), 0, stream>>>(
        Wo, Wo_t, 1024, 1024, 1024, 0L, 0L);
    tcvt_kernel<<<dim3(128, 32, 1), dim3(32, 8), 0, stream>>>(
        W1, W1_t, 1024, 4096, 1024, 0L, 0L);
    tcvt_kernel<<<dim3(32, 128, 1), dim3(32, 8), 0, stream>>>(
        W2, W2_t, 4096, 1024, 4096, 0L, 0L);

    // 1) h = LN(x) -> bf16
    ln_kernel<<<dim3(BT_), dim3(256), 0, stream>>>(x, g1, be1, h_bf);

    // 2a) qk = h @ [Wq|Wk]^T   [4096][2048]
    gemm_bf16<0, true><<<dim3(2048/128, BT_/128), dim3(256), 0, stream>>>(
        h_bf, qkvw, qk_act, nullptr, nullptr, BT_, 2048, C_);
    // 2b) vt = Wv^T-rows @ h^T  -> V^T [1024][4096]  (swapped operands)
    gemm_bf16<0, true><<<dim3(BT_/128, 1024/128), dim3(256), 0, stream>>>(
        qkvw + (size_t)2*1024*1024, h_bf, vt, nullptr, nullptr, 1024, BT_, C_);

    // 3) attention (MFMA flash, KVBLK=128 staged / 64 processed, prefetched)
    attn_mfma<<<dim3(16, B_*H_), dim3(256), 0, stream>>>(qk_act, vt, attn_bf);

    // 4) out = x + attn @ Wo + bo   (fp32 out)
    gemm_bf16<1|4, false><<<dim3(1024/128, BT_/128), dim3(256), 0, stream>>>(
        attn_bf, Wo_t, out, bo, x, BT_, C_, C_);

    // 5) h2 = LN(out) -> bf16
    ln_kernel<<<dim3(BT_), dim3(256), 0, stream>>>(out, g2, be2, h_bf);

    // 6) ff1 = relu(h2 @ W1 + b1) -> bf16
    gemm_bf16<1|2, true><<<dim3(4096/128, BT_/128), dim3(256), 0, stream>>>(
        h_bf, W1_t, ff1, b1, nullptr, BT_, FF_, C_);

    // 7) out = out + ff1 @ W2 + b2  (fp32, residual = out itself)
    gemm_bf16<1|4, false><<<dim3(1024/128, BT_/128), dim3(256), 0, stream>>>(
        ff1, W2_t, out, b2, out, BT_, C_, FF_);
}

// Round 6
// 333.452 us; speedup vs baseline: 1.1553x; 1.0628x over previous
//
#include <hip/hip_runtime.h>
#include <hip/hip_bf16.h>
#include <cstdint>
#include <cstddef>
#include <cstring>

#define B_ 2
#define T_ 2048
#define C_ 1024
#define H_ 16
#define HD_ 64
#define FF_ 4096
#define BT_ (B_*T_)   // 4096 rows

typedef __attribute__((ext_vector_type(8))) short short8;
typedef __attribute__((ext_vector_type(4))) float f32x4;

__device__ __forceinline__ ushort f2bf(float f) {
    uint x = __float_as_uint(f);
    return (ushort)((x + 0x7fffu + ((x >> 16) & 1u)) >> 16);
}
// hot-path convert: scalar cast so compiler can fuse v_cvt_pk_bf16_f32 (m240)
__device__ __forceinline__ ushort f2bf_hw(float f) {
    __hip_bfloat16 h = __float2bfloat16(f);
    ushort u;
    __builtin_memcpy(&u, &h, 2);
    return u;
}

#define GLDS16(g, l)                                                        \
    __builtin_amdgcn_global_load_lds(                                       \
        (const __attribute__((address_space(1))) void*)(g),                 \
        (__attribute__((address_space(3))) void*)(l), 16, 0, 0)

// ---------------------------------------------------------------------------
// LayerNorm: one block (256 threads) per row of C_=1024, fp32 in, bf16 out.
// ---------------------------------------------------------------------------
__global__ __launch_bounds__(256) void ln_kernel(const float* __restrict__ x,
                                                 const float* __restrict__ g,
                                                 const float* __restrict__ b,
                                                 ushort* __restrict__ out) {
    int row = blockIdx.x;
    int tid = threadIdx.x;
    const float* xr = x + (size_t)row * C_;
    float4 v = *(const float4*)(xr + tid * 4);
    float s = v.x + v.y + v.z + v.w;
    float q = v.x*v.x + v.y*v.y + v.z*v.z + v.w*v.w;
    #pragma unroll
    for (int off = 32; off > 0; off >>= 1) {
        s += __shfl_down(s, off);
        q += __shfl_down(q, off);
    }
    __shared__ float ss[4], qs[4];
    if ((tid & 63) == 0) { ss[tid >> 6] = s; qs[tid >> 6] = q; }
    __syncthreads();
    s = ss[0] + ss[1] + ss[2] + ss[3];
    q = qs[0] + qs[1] + qs[2] + qs[3];
    float mu  = s * (1.0f / C_);
    float var = q * (1.0f / C_) - mu * mu;
    float r = rsqrtf(var + 1e-5f);
    float4 gv = *(const float4*)(g + tid * 4);
    float4 bv = *(const float4*)(b + tid * 4);
    ushort4 o;
    o.x = f2bf((v.x - mu) * r * gv.x + bv.x);
    o.y = f2bf((v.y - mu) * r * gv.y + bv.y);
    o.z = f2bf((v.z - mu) * r * gv.z + bv.z);
    o.w = f2bf((v.w - mu) * r * gv.w + bv.w);
    *(ushort4*)(out + (size_t)row * C_ + tid * 4) = o;
}

// ---------------------------------------------------------------------------
// Tiled transpose + fp32->bf16 convert. (weights, once per call)
// ---------------------------------------------------------------------------
__global__ __launch_bounds__(256) void tcvt_kernel(const float* __restrict__ in,
                                                   ushort* __restrict__ out,
                                                   int R, int Cc, int ldo,
                                                   long in_bs, long out_bs) {
    __shared__ float tile[32][33];
    const float* inz = in + (size_t)blockIdx.z * in_bs;
    ushort* outz = out + (size_t)blockIdx.z * out_bs;
    int c0 = blockIdx.x * 32, r0 = blockIdx.y * 32;
    #pragma unroll
    for (int i = 0; i < 4; i++) {
        int r = threadIdx.y + i * 8;
        tile[r][threadIdx.x] = inz[(size_t)(r0 + r) * Cc + c0 + threadIdx.x];
    }
    __syncthreads();
    #pragma unroll
    for (int i = 0; i < 4; i++) {
        int c = threadIdx.y + i * 8;
        outz[(size_t)(c0 + c) * ldo + r0 + threadIdx.x] = f2bf(tile[threadIdx.x][c]);
    }
}

// ---------------------------------------------------------------------------
// bf16 MFMA GEMM: 128x128 tile, BK=32, 4 waves, 2-phase double-buffered
// staging (prefetch k+1 issued before compute k; one barrier per K-step)
// + bijective XCD-aware workgroup swizzle (T1; requires nwg % 8 == 0).
// A [M][K] bf16, Bt [N][K] bf16. EPI: 1=bias, 2=relu, 4=residual fp32.
// ---------------------------------------------------------------------------
template<int EPI, bool OUT_BF16>
__global__ __launch_bounds__(256) void gemm_bf16(
    const ushort* __restrict__ A,
    const ushort* __restrict__ Bt,
    void* __restrict__ Cout,
    const float* __restrict__ bias,
    const float* __restrict__ resid,
    int M, int N, int K)
{
    __shared__ ushort As[2][128 * 32];
    __shared__ ushort Bs[2][128 * 32];

    // T1: flat-id XCD swizzle (consecutive logical tiles -> same XCD L2)
    int gx = gridDim.x;
    int nwg = gx * gridDim.y;
    int bid = blockIdx.y * gx + blockIdx.x;
    int cpx = nwg >> 3;                    // nwg % 8 == 0 at all call sites
    int swz = (bid & 7) * cpx + (bid >> 3);
    int bx = swz % gx, by = swz / gx;

    int tid  = threadIdx.x;
    int lane = tid & 63;
    int lr = lane & 15, lq = lane >> 4;
    int wave = tid >> 6;
    int wr = wave >> 1, wc = wave & 1;
    int m0 = by * 128, n0 = bx * 128;

    f32x4 acc[4][4];
    #pragma unroll
    for (int m = 0; m < 4; m++)
        #pragma unroll
        for (int n = 0; n < 4; n++)
            acc[m][n] = {0.f, 0.f, 0.f, 0.f};

    int arow = tid >> 2;
    int acol = (tid & 3) * 8;
    const ushort* ga = A  + (size_t)(m0 + arow) * K + acol;
    const ushort* gb = Bt + (size_t)(n0 + arow) * K + acol;
    int lbase = wave * 1024;

    auto stage = [&](int k0, int buf) {
        GLDS16(ga + k0,                (char*)As[buf] + lbase);
        GLDS16(ga + 64*(size_t)K + k0, (char*)As[buf] + 4096 + lbase);
        GLDS16(gb + k0,                (char*)Bs[buf] + lbase);
        GLDS16(gb + 64*(size_t)K + k0, (char*)Bs[buf] + 4096 + lbase);
    };

    stage(0, 0);
    __syncthreads();          // drain: tile 0 visible
    int cur = 0;

    for (int k0 = 0; k0 < K; k0 += 32) {
        if (k0 + 32 < K) stage(k0 + 32, cur ^ 1);   // prefetch under compute

        const ushort* Ac = As[cur];
        const ushort* Bc = Bs[cur];
        short8 a[4], b[4];
        #pragma unroll
        for (int m = 0; m < 4; m++)
            a[m] = *(const short8*)(Ac + (wr*64 + m*16 + lr) * 32 + lq*8);
        #pragma unroll
        for (int n = 0; n < 4; n++)
            b[n] = *(const short8*)(Bc + (wc*64 + n*16 + lr) * 32 + lq*8);
        #pragma unroll
        for (int m = 0; m < 4; m++)
            #pragma unroll
            for (int n = 0; n < 4; n++)
                acc[m][n] = __builtin_amdgcn_mfma_f32_16x16x32_bf16(
                    a[m], b[n], acc[m][n], 0, 0, 0);

        __syncthreads();      // all waves done with buf[cur]; prefetch drained
        cur ^= 1;
    }

    #pragma unroll
    for (int m = 0; m < 4; m++) {
        #pragma unroll
        for (int n = 0; n < 4; n++) {
            int col = n0 + wc*64 + n*16 + lr;
            #pragma unroll
            for (int j = 0; j < 4; j++) {
                int row = m0 + wr*64 + m*16 + lq*4 + j;
                float v = acc[m][n][j];
                if (EPI & 1) v += bias[col];
                if (EPI & 2) v = fmaxf(v, 0.f);
                if (EPI & 4) v += resid[(size_t)row * N + col];
                if (OUT_BF16)
                    ((ushort*)Cout)[(size_t)row * N + col] = f2bf(v);
                else
                    ((float*)Cout)[(size_t)row * N + col] = v;
            }
        }
    }
}

// ---------------------------------------------------------------------------
// MFMA causal flash attention, KVBLK=128 staged, processed in 64-key halves.
// Double-buffered K/V with prefetch (2-phase).
// qk : [BT_][2048] bf16 (q at h*64, k at 1024+h*64)
// vt : [1024][4096] bf16 = V^T, row = h*64+d, col = bb*2048+s
// out: [BT_][1024] bf16
// ---------------------------------------------------------------------------
__global__ __launch_bounds__(256) void attn_mfma(const ushort* __restrict__ qk,
                                                 const ushort* __restrict__ vt,
                                                 ushort* __restrict__ attn_out) {
    const float C2 = 0.18033688011f;     // 0.125 * log2(e)
    const float THR2 = 12.0f;            // defer-max threshold (log2 domain)

    int bh = blockIdx.y;
    int bb = bh >> 4;
    int head = bh & 15;
    int qa = 15 - blockIdx.x;            // heavy tiles first
    int q0 = qa * 128;

    int tid  = threadIdx.x;
    int lane = tid & 63;
    int lr = lane & 15, lq = lane >> 4;
    int wave = tid >> 6;
    int qw = q0 + wave * 32;

    __shared__ ushort Ks[2][128 * 64];   // 2 x 16KB [key][d], swizzled slots
    __shared__ ushort Vs[2][64 * 128];   // 2 x 16KB [d][key], swizzled
    __shared__ ushort Ps[4][32 * 64];    // 16KB per-wave P [q][k64], swizzled

    // Q fragments (held in registers the whole kernel)
    short8 qf[2][2];
    {
        const ushort* qb = qk + ((size_t)(bb * T_ + qw)) * 2048 + head * 64;
        #pragma unroll
        for (int mt = 0; mt < 2; mt++)
            #pragma unroll
            for (int kk = 0; kk < 2; kk++)
                qf[mt][kk] = *(const short8*)(qb + (size_t)(mt*16 + lr) * 2048 + kk*32 + lq*8);
    }

    f32x4 acc[2][4];
    f32x4 lsum[2];
    float m2[2][4];
    #pragma unroll
    for (int mt = 0; mt < 2; mt++) {
        #pragma unroll
        for (int dt = 0; dt < 4; dt++) acc[mt][dt] = {0.f, 0.f, 0.f, 0.f};
        lsum[mt] = {0.f, 0.f, 0.f, 0.f};
        #pragma unroll
        for (int j = 0; j < 4; j++) m2[mt][j] = -INFINITY;
    }

    const short8 onesf = {(short)0x3F80, (short)0x3F80, (short)0x3F80, (short)0x3F80,
                          (short)0x3F80, (short)0x3F80, (short)0x3F80, (short)0x3F80};

    // staging geometry (pre-swizzled global source, linear LDS dest)
    int krow = tid >> 3;                       // 0..31
    int ksc = ((tid & 7) ^ (krow & 7)) * 8;
    const ushort* kg0 = qk + ((size_t)(bb * T_ + krow)) * 2048 + 1024 + head * 64 + ksc;
    int vrow = tid >> 4;                       // 0..15
    int vsc = ((tid & 15) ^ (vrow & 7)) * 8;
    const ushort* vg0 = vt + ((size_t)(head * 64 + vrow)) * 4096 + (size_t)bb * 2048 + vsc;

    auto stage = [&](int it, int buf) {
        int s0 = it * 128;
        char* Kb = (char*)Ks[buf] + wave * 1024;
        char* Vb = (char*)Vs[buf] + wave * 1024;
        #pragma unroll
        for (int i = 0; i < 4; i++)
            GLDS16(kg0 + (size_t)(s0 + i*32) * 2048, Kb + i*4096);
        #pragma unroll
        for (int i = 0; i < 4; i++)
            GLDS16(vg0 + (size_t)(i*16) * 4096 + s0, Vb + i*4096);
    };

    int nt = qa + 1;
    stage(0, 0);
    __syncthreads();                      // drain: tile 0 visible
    int cur = 0;

    for (int it = 0; it < nt; it++) {
        if (it + 1 < nt) stage(it + 1, cur ^ 1);   // prefetch under compute

        const ushort* Kc = Ks[cur];
        const ushort* Vc = Vs[cur];
        #pragma unroll
        for (int h = 0; h < 2; h++) {
            int s0h = it * 128 + h * 64;
            if (s0h > qw + 31) continue;           // wave-uniform causal skip

            // ---- S = Q K^T (64 keys) ----
            f32x4 sa[2][4];
            __builtin_amdgcn_s_setprio(1);
            #pragma unroll
            for (int n = 0; n < 4; n++) {
                int row = h*64 + n*16 + lr;
                const char* kbase = (const char*)Kc + row*128;
                short8 kf0 = *(const short8*)(kbase + ((lq       ^ (row & 7)) << 4));
                short8 kf1 = *(const short8*)(kbase + (((4 + lq) ^ (row & 7)) << 4));
                #pragma unroll
                for (int mt = 0; mt < 2; mt++) {
                    f32x4 t = {0.f, 0.f, 0.f, 0.f};
                    t = __builtin_amdgcn_mfma_f32_16x16x32_bf16(qf[mt][0], kf0, t, 0, 0, 0);
                    t = __builtin_amdgcn_mfma_f32_16x16x32_bf16(qf[mt][1], kf1, t, 0, 0, 0);
                    sa[mt][n] = t;
                }
            }
            __builtin_amdgcn_s_setprio(0);

            // ---- causal mask (diagonal half only; wave-uniform branch) ----
            if (s0h + 63 > qw) {
                #pragma unroll
                for (int mt = 0; mt < 2; mt++)
                    #pragma unroll
                    for (int n = 0; n < 4; n++)
                        #pragma unroll
                        for (int j = 0; j < 4; j++) {
                            int scol = s0h + n*16 + lr;
                            int qrow = qw + mt*16 + lq*4 + j;
                            if (scol > qrow) sa[mt][n][j] = -INFINITY;
                        }
            }

            // ---- row maxes (log2-scaled) + defer-max vote ----
            float vmax2[2][4];
            bool grow = false;
            #pragma unroll
            for (int mt = 0; mt < 2; mt++) {
                #pragma unroll
                for (int j = 0; j < 4; j++) {
                    float v = fmaxf(fmaxf(sa[mt][0][j], sa[mt][1][j]),
                                    fmaxf(sa[mt][2][j], sa[mt][3][j]));
                    #pragma unroll
                    for (int off = 1; off < 16; off <<= 1)
                        v = fmaxf(v, __shfl_xor(v, off));
                    float v2 = v * C2;
                    vmax2[mt][j] = v2;
                    grow |= (v2 > m2[mt][j] + THR2);
                }
            }
            if (__any(grow)) {
                #pragma unroll
                for (int mt = 0; mt < 2; mt++)
                    #pragma unroll
                    for (int j = 0; j < 4; j++) {
                        float m2n = fmaxf(m2[mt][j], vmax2[mt][j]);
                        float corr = __builtin_amdgcn_exp2f(m2[mt][j] - m2n);
                        m2[mt][j] = m2n;
                        lsum[mt][j] *= corr;
                        #pragma unroll
                        for (int dt = 0; dt < 4; dt++)
                            acc[mt][dt][j] *= corr;
                    }
            }

            // ---- P = exp2(s*C2 - m2) -> bf16 -> per-wave swizzled LDS ----
            char* pw = (char*)Ps[wave];
            #pragma unroll
            for (int mt = 0; mt < 2; mt++)
                #pragma unroll
                for (int n = 0; n < 4; n++)
                    #pragma unroll
                    for (int j = 0; j < 4; j++) {
                        float p = __builtin_amdgcn_exp2f(
                            fmaf(sa[mt][n][j], C2, -m2[mt][j]));
                        int row = mt*16 + lq*4 + j;
                        int col = n*16 + lr;
                        int byte = row*128 + ((((col >> 3) ^ (row & 7))) << 4) + (col & 7)*2;
                        *(ushort*)(pw + byte) = f2bf_hw(p);
                    }

            // ---- read P fragments; lsum += P*1; O += P V ----
            short8 pf[2][2];
            #pragma unroll
            for (int mt = 0; mt < 2; mt++) {
                int row = mt*16 + lr;
                #pragma unroll
                for (int kk = 0; kk < 2; kk++)
                    pf[mt][kk] = *(const short8*)(pw + row*128
                                   + (((kk*4 + lq) ^ (row & 7)) << 4));
            }
            __builtin_amdgcn_s_setprio(1);
            #pragma unroll
            for (int kk = 0; kk < 2; kk++)
                #pragma unroll
                for (int mt = 0; mt < 2; mt++)
                    lsum[mt] = __builtin_amdgcn_mfma_f32_16x16x32_bf16(
                        pf[mt][kk], onesf, lsum[mt], 0, 0, 0);
            #pragma unroll
            for (int dt = 0; dt < 4; dt++) {
                int row = dt*16 + lr;
                const char* vbase = (const char*)Vc + row*256;
                #pragma unroll
                for (int kk = 0; kk < 2; kk++) {
                    short8 vf = *(const short8*)(vbase
                                  + ((((h*2 + kk)*4 + lq) ^ (row & 7)) << 4));
                    #pragma unroll
                    for (int mt = 0; mt < 2; mt++)
                        acc[mt][dt] = __builtin_amdgcn_mfma_f32_16x16x32_bf16(
                            pf[mt][kk], vf, acc[mt][dt], 0, 0, 0);
                }
            }
            __builtin_amdgcn_s_setprio(0);
        }

        __syncthreads();   // all waves done with buf[cur]; prefetched loads drained
        cur ^= 1;
    }

    // ---- epilogue: O / lsum ----
    ushort* ob = attn_out + ((size_t)(bb * T_ + qw)) * 1024 + head * 64;
    #pragma unroll
    for (int mt = 0; mt < 2; mt++)
        #pragma unroll
        for (int j = 0; j < 4; j++) {
            float inv = 1.0f / lsum[mt][j];
            #pragma unroll
            for (int dt = 0; dt < 4; dt++)
                ob[(size_t)(mt*16 + lq*4 + j) * 1024 + dt*16 + lr] =
                    f2bf(acc[mt][dt][j] * inv);
        }
}

// ---------------------------------------------------------------------------
extern "C" void kernel_launch(void* const* d_in, const int* in_sizes, int n_in,
                              void* d_out, int out_size, void* d_ws, size_t ws_size,
                              hipStream_t stream) {
    const float* x   = (const float*)d_in[0];
    const float* Wq  = (const float*)d_in[1];
    const float* Wk  = (const float*)d_in[2];
    const float* Wv  = (const float*)d_in[3];
    const float* Wo  = (const float*)d_in[4];
    const float* bo  = (const float*)d_in[5];
    const float* W1  = (const float*)d_in[6];
    const float* b1  = (const float*)d_in[7];
    const float* W2  = (const float*)d_in[8];
    const float* b2  = (const float*)d_in[9];
    const float* g1  = (const float*)d_in[10];
    const float* be1 = (const float*)d_in[11];
    const float* g2  = (const float*)d_in[12];
    const float* be2 = (const float*)d_in[13];
    float* out = (float*)d_out;

    char* ws = (char*)d_ws;
    const size_t MB = 1 << 20;
    ushort* h_bf    = (ushort*)(ws);                 // 8 MB
    ushort* qk_act  = (ushort*)(ws + 8*MB);          // 16 MB [4096][2048]
    ushort* vt      = (ushort*)(ws + 24*MB);         // 8 MB  [1024][4096] V^T
    ushort* attn_bf = (ushort*)(ws + 32*MB);         // 8 MB  [4096][1024]
    ushort* ff1     = (ushort*)(ws + 8*MB);          // 32 MB (reuses qk/vt/attn)
    ushort* qkvw    = (ushort*)(ws + 40*MB);         // 6 MB  [3072][1024]
    ushort* Wo_t    = (ushort*)(ws + 46*MB);         // 2 MB
    ushort* W1_t    = (ushort*)(ws + 48*MB);         // 8 MB
    ushort* W2_t    = (ushort*)(ws + 56*MB);         // 8 MB

    // --- weight transposes + bf16 convert ---
    const float* Wsrc[3] = {Wq, Wk, Wv};
    for (int w = 0; w < 3; w++) {
        tcvt_kernel<<<dim3(2, 32, 16), dim3(32, 8), 0, stream>>>(
            Wsrc[w], qkvw + (size_t)w * 1024 * 1024,
            1024, 64, 1024, 65536L, 65536L);
    }
    tcvt_kernel<<<dim3(32, 32, 1), dim3(32, 8), 0, stream>>>(
        Wo, Wo_t, 1024, 1024, 1024, 0L, 0L);
    tcvt_kernel<<<dim3(128, 32, 1), dim3(32, 8), 0, stream>>>(
        W1, W1_t, 1024, 4096, 1024, 0L, 0L);
    tcvt_kernel<<<dim3(32, 128, 1), dim3(32, 8), 0, stream>>>(
        W2, W2_t, 4096, 1024, 4096, 0L, 0L);

    // 1) h = LN(x) -> bf16
    ln_kernel<<<dim3(BT_), dim3(256), 0, stream>>>(x, g1, be1, h_bf);

    // 2a) qk = h @ [Wq|Wk]^T   [4096][2048]
    gemm_bf16<0, true><<<dim3(2048/128, BT_/128), dim3(256), 0, stream>>>(
        h_bf, qkvw, qk_act, nullptr, nullptr, BT_, 2048, C_);
    // 2b) vt = Wv^T-rows @ h^T  -> V^T [1024][4096]  (swapped operands)
    gemm_bf16<0, true><<<dim3(BT_/128, 1024/128), dim3(256), 0, stream>>>(
        qkvw + (size_t)2*1024*1024, h_bf, vt, nullptr, nullptr, 1024, BT_, C_);

    // 3) attention (MFMA flash, KVBLK=128 staged / 64 processed, prefetched)
    attn_mfma<<<dim3(16, B_*H_), dim3(256), 0, stream>>>(qk_act, vt, attn_bf);

    // 4) out = x + attn @ Wo + bo   (fp32 out)
    gemm_bf16<1|4, false><<<dim3(1024/128, BT_/128), dim3(256), 0, stream>>>(
        attn_bf, Wo_t, out, bo, x, BT_, C_, C_);

    // 5) h2 = LN(out) -> bf16
    ln_kernel<<<dim3(BT_), dim3(256), 0, stream>>>(out, g2, be2, h_bf);

    // 6) ff1 = relu(h2 @ W1 + b1) -> bf16
    gemm_bf16<1|2, true><<<dim3(4096/128, BT_/128), dim3(256), 0, stream>>>(
        h_bf, W1_t, ff1, b1, nullptr, BT_, FF_, C_);

    // 7) out = out + ff1 @ W2 + b2  (fp32, residual = out itself)
    gemm_bf16<1|4, false><<<dim3(1024/128, BT_/128), dim3(256), 0, stream>>>(
        ff1, W2_t, out, b2, out, BT_, C_, FF_);
}

// Round 7
// 325.828 us; speedup vs baseline: 1.1823x; 1.0234x over previous
//
#include <hip/hip_runtime.h>
#include <hip/hip_bf16.h>
#include <cstdint>
#include <cstddef>
#include <cstring>

#define B_ 2
#define T_ 2048
#define C_ 1024
#define H_ 16
#define HD_ 64
#define FF_ 4096
#define BT_ (B_*T_)   // 4096 rows

typedef __attribute__((ext_vector_type(8))) short short8;
typedef __attribute__((ext_vector_type(4))) float f32x4;

__device__ __forceinline__ float bf2f(ushort u) {
    return __uint_as_float(((uint)u) << 16);
}
__device__ __forceinline__ ushort f2bf(float f) {
    uint x = __float_as_uint(f);
    return (ushort)((x + 0x7fffu + ((x >> 16) & 1u)) >> 16);
}
// hot-path convert: scalar cast so compiler can fuse v_cvt_pk_bf16_f32 (m240)
__device__ __forceinline__ ushort f2bf_hw(float f) {
    __hip_bfloat16 h = __float2bfloat16(f);
    ushort u;
    __builtin_memcpy(&u, &h, 2);
    return u;
}

#define GLDS16(g, l)                                                        \
    __builtin_amdgcn_global_load_lds(                                       \
        (const __attribute__((address_space(1))) void*)(g),                 \
        (__attribute__((address_space(3))) void*)(l), 16, 0, 0)

// ---------------------------------------------------------------------------
// LayerNorm: one block (256 threads) per row of C_=1024, fp32 in, bf16 out.
// ---------------------------------------------------------------------------
__global__ __launch_bounds__(256) void ln_kernel(const float* __restrict__ x,
                                                 const float* __restrict__ g,
                                                 const float* __restrict__ b,
                                                 ushort* __restrict__ out) {
    int row = blockIdx.x;
    int tid = threadIdx.x;
    const float* xr = x + (size_t)row * C_;
    float4 v = *(const float4*)(xr + tid * 4);
    float s = v.x + v.y + v.z + v.w;
    float q = v.x*v.x + v.y*v.y + v.z*v.z + v.w*v.w;
    #pragma unroll
    for (int off = 32; off > 0; off >>= 1) {
        s += __shfl_down(s, off);
        q += __shfl_down(q, off);
    }
    __shared__ float ss[4], qs[4];
    if ((tid & 63) == 0) { ss[tid >> 6] = s; qs[tid >> 6] = q; }
    __syncthreads();
    s = ss[0] + ss[1] + ss[2] + ss[3];
    q = qs[0] + qs[1] + qs[2] + qs[3];
    float mu  = s * (1.0f / C_);
    float var = q * (1.0f / C_) - mu * mu;
    float r = rsqrtf(var + 1e-5f);
    float4 gv = *(const float4*)(g + tid * 4);
    float4 bv = *(const float4*)(b + tid * 4);
    ushort4 o;
    o.x = f2bf((v.x - mu) * r * gv.x + bv.x);
    o.y = f2bf((v.y - mu) * r * gv.y + bv.y);
    o.z = f2bf((v.z - mu) * r * gv.z + bv.z);
    o.w = f2bf((v.w - mu) * r * gv.w + bv.w);
    *(ushort4*)(out + (size_t)row * C_ + tid * 4) = o;
}

// ---------------------------------------------------------------------------
// Tiled transpose + fp32->bf16 convert. (weights, once per call)
// ---------------------------------------------------------------------------
__global__ __launch_bounds__(256) void tcvt_kernel(const float* __restrict__ in,
                                                   ushort* __restrict__ out,
                                                   int R, int Cc, int ldo,
                                                   long in_bs, long out_bs) {
    __shared__ float tile[32][33];
    const float* inz = in + (size_t)blockIdx.z * in_bs;
    ushort* outz = out + (size_t)blockIdx.z * out_bs;
    int c0 = blockIdx.x * 32, r0 = blockIdx.y * 32;
    #pragma unroll
    for (int i = 0; i < 4; i++) {
        int r = threadIdx.y + i * 8;
        tile[r][threadIdx.x] = inz[(size_t)(r0 + r) * Cc + c0 + threadIdx.x];
    }
    __syncthreads();
    #pragma unroll
    for (int i = 0; i < 4; i++) {
        int c = threadIdx.y + i * 8;
        outz[(size_t)(c0 + c) * ldo + r0 + threadIdx.x] = f2bf(tile[threadIdx.x][c]);
    }
}

// ---------------------------------------------------------------------------
// bf16 MFMA GEMM, phase-structured (T2+T3+T4+T5+T1):
// BM=128 x BN=256, BK=64, 512 thr = 8 waves (2Mr x 4Nc), wave owns 64x64.
// Per K-tile: 2 phases x 16 MFMA, raw s_barrier (no vmcnt drain), counted
// vmcnt(6) only at tile boundary; tile t+2 staged while t+1 is in flight.
// LDS XOR-swizzled (linear gl_lds dest + inverse-swizzled global source).
// A [M][K] bf16, Bt [N][K] bf16. EPI: 1=bias, 2=relu, 4=residual fp32.
// Split-K via gridDim.z: Koff = z*KS, output z-slab at Cout + z*M*N.
// ---------------------------------------------------------------------------
template<int EPI, bool OUT_BF16>
__global__ __launch_bounds__(512, 2) void gemm2(
    const ushort* __restrict__ A,
    const ushort* __restrict__ Bt,
    void* __restrict__ Cout,
    const float* __restrict__ bias,
    const float* __restrict__ resid,
    int M, int N, int K, int KS)
{
    __shared__ ushort As[2][128 * 64];   // 2 x 16 KB
    __shared__ ushort Bs[2][256 * 64];   // 2 x 32 KB

    // T1: bijective XCD swizzle over the (x,y) grid (nwg % 8 == 0 everywhere)
    int gx = gridDim.x;
    int nwg = gx * gridDim.y;
    int bid = blockIdx.y * gx + blockIdx.x;
    int cpx = nwg >> 3;
    int swz = (bid & 7) * cpx + (bid >> 3);
    int bx = swz % gx, by = swz / gx;

    int tid  = threadIdx.x;
    int lane = tid & 63;
    int lr = lane & 15, lq = lane >> 4;
    int wave = tid >> 6;                 // 0..7
    int wr = wave >> 2, wc = wave & 3;
    int m0 = by * 128, n0 = bx * 256;
    int Koff = blockIdx.z * KS;
    size_t zoff = (size_t)blockIdx.z * ((size_t)M * N);

    f32x4 acc[4][4];
    #pragma unroll
    for (int i = 0; i < 4; i++)
        #pragma unroll
        for (int j = 0; j < 4; j++)
            acc[i][j] = {0.f, 0.f, 0.f, 0.f};

    // staging: thread covers row (i*64 + tid/8), 16B slot tid%8 (linear LDS);
    // global source col pre-swizzled so LDS[r][slot] = data[r][slot ^ (r&7)]
    int srow = tid >> 3;
    int scol = ((tid & 7) ^ (srow & 7)) * 8;
    const ushort* gA = A  + (size_t)(m0 + srow) * K + Koff + scol;
    const ushort* gB = Bt + (size_t)(n0 + srow) * K + Koff + scol;
    int NT = KS / 64;

    auto stage = [&](int kt, int buf) {
        const ushort* a = gA + kt * 64;
        const ushort* b = gB + kt * 64;
        char* la = (char*)As[buf] + wave * 1024;
        char* lb = (char*)Bs[buf] + wave * 1024;
        GLDS16(a, la);
        GLDS16(a + (size_t)64 * K, la + 8192);
        #pragma unroll
        for (int i = 0; i < 4; i++)
            GLDS16(b + (size_t)i * 64 * K, lb + i * 8192);
    };

    stage(0, 0);
    stage(1, 1);
    asm volatile("s_waitcnt vmcnt(6)" ::: "memory");   // tile 0 landed; tile 1 in flight
    __builtin_amdgcn_s_barrier();

    // swizzled read offsets: byte slot = ((kh*4+lq) ^ (lr&7)) << 4
    int sx4 = (lr & 7) << 4;
    int so0 = (lq << 4) ^ sx4;
    int so1 = ((4 + lq) << 4) ^ sx4;

    int cur = 0;
    for (int t = 0; t < NT; ++t) {
        const char* Ab = (const char*)As[cur] + (wr * 64 + lr) * 128;
        const char* Bb = (const char*)Bs[cur] + (wc * 64 + lr) * 128;

        // ---- phase 0: read B (all 4 cols) + A rows 0,1; 16 MFMA ----
        short8 bf[4][2], af[2][2];
        #pragma unroll
        for (int fc = 0; fc < 4; fc++) {
            bf[fc][0] = *(const short8*)(Bb + fc * 2048 + so0);
            bf[fc][1] = *(const short8*)(Bb + fc * 2048 + so1);
        }
        #pragma unroll
        for (int r = 0; r < 2; r++) {
            af[r][0] = *(const short8*)(Ab + r * 2048 + so0);
            af[r][1] = *(const short8*)(Ab + r * 2048 + so1);
        }
        __builtin_amdgcn_s_barrier();
        __builtin_amdgcn_s_setprio(1);
        #pragma unroll
        for (int r = 0; r < 2; r++)
            #pragma unroll
            for (int fc = 0; fc < 4; fc++) {
                acc[r][fc] = __builtin_amdgcn_mfma_f32_16x16x32_bf16(
                    af[r][0], bf[fc][0], acc[r][fc], 0, 0, 0);
                acc[r][fc] = __builtin_amdgcn_mfma_f32_16x16x32_bf16(
                    af[r][1], bf[fc][1], acc[r][fc], 0, 0, 0);
            }
        __builtin_amdgcn_s_setprio(0);
        __builtin_amdgcn_s_barrier();

        // ---- phase 1: read A rows 2,3; 16 MFMA ----
        #pragma unroll
        for (int r = 0; r < 2; r++) {
            af[r][0] = *(const short8*)(Ab + (2 + r) * 2048 + so0);
            af[r][1] = *(const short8*)(Ab + (2 + r) * 2048 + so1);
        }
        __builtin_amdgcn_s_barrier();
        __builtin_amdgcn_s_setprio(1);
        #pragma unroll
        for (int r = 0; r < 2; r++)
            #pragma unroll
            for (int fc = 0; fc < 4; fc++) {
                acc[2 + r][fc] = __builtin_amdgcn_mfma_f32_16x16x32_bf16(
                    af[r][0], bf[fc][0], acc[2 + r][fc], 0, 0, 0);
                acc[2 + r][fc] = __builtin_amdgcn_mfma_f32_16x16x32_bf16(
                    af[r][1], bf[fc][1], acc[2 + r][fc], 0, 0, 0);
            }
        __builtin_amdgcn_s_setprio(0);
        __builtin_amdgcn_s_barrier();     // all waves done reading slot cur

        if (t + 1 == NT) break;
        if (t + 2 < NT) {
            stage(t + 2, cur);            // overwrite just-freed slot
            asm volatile("s_waitcnt vmcnt(6)" ::: "memory");  // t+1 landed; t+2 in flight
        } else {
            asm volatile("s_waitcnt vmcnt(0)" ::: "memory");
        }
        __builtin_amdgcn_s_barrier();
        cur ^= 1;
    }

    // ---- epilogue ----
    #pragma unroll
    for (int fr = 0; fr < 4; fr++) {
        #pragma unroll
        for (int fc = 0; fc < 4; fc++) {
            int col = n0 + wc * 64 + fc * 16 + lr;
            #pragma unroll
            for (int j = 0; j < 4; j++) {
                int row = m0 + wr * 64 + fr * 16 + lq * 4 + j;
                float v = acc[fr][fc][j];
                if (EPI & 1) v += bias[col];
                if (EPI & 2) v = fmaxf(v, 0.f);
                if (EPI & 4) v += resid[(size_t)row * N + col];
                if (OUT_BF16)
                    ((ushort*)Cout)[zoff + (size_t)row * N + col] = f2bf(v);
                else
                    ((float*)Cout)[zoff + (size_t)row * N + col] = v;
            }
        }
    }
}

// ---------------------------------------------------------------------------
// FF2 split-K finalize: out += p0 + p1 + b2   (p bf16 partials, out fp32)
// ---------------------------------------------------------------------------
__global__ __launch_bounds__(256) void ff2_red(float* __restrict__ out,
                                               const ushort* __restrict__ p,
                                               const float* __restrict__ b2) {
    size_t i = (size_t)blockIdx.x * 256 + threadIdx.x;   // 4-elem groups
    float4 o = ((float4*)out)[i];
    ushort4 a = ((const ushort4*)p)[i];
    ushort4 b = ((const ushort4*)(p + (size_t)BT_ * C_))[i];
    float4 c = ((const float4*)b2)[i & 255];
    o.x += bf2f(a.x) + bf2f(b.x) + c.x;
    o.y += bf2f(a.y) + bf2f(b.y) + c.y;
    o.z += bf2f(a.z) + bf2f(b.z) + c.z;
    o.w += bf2f(a.w) + bf2f(b.w) + c.w;
    ((float4*)out)[i] = o;
}

// ---------------------------------------------------------------------------
// MFMA causal flash attention, KVBLK=128 staged, processed in 64-key halves.
// Double-buffered K/V with prefetch (2-phase).
// ---------------------------------------------------------------------------
__global__ __launch_bounds__(256) void attn_mfma(const ushort* __restrict__ qk,
                                                 const ushort* __restrict__ vt,
                                                 ushort* __restrict__ attn_out) {
    const float C2 = 0.18033688011f;     // 0.125 * log2(e)
    const float THR2 = 12.0f;            // defer-max threshold (log2 domain)

    int bh = blockIdx.y;
    int bb = bh >> 4;
    int head = bh & 15;
    int qa = 15 - blockIdx.x;            // heavy tiles first
    int q0 = qa * 128;

    int tid  = threadIdx.x;
    int lane = tid & 63;
    int lr = lane & 15, lq = lane >> 4;
    int wave = tid >> 6;
    int qw = q0 + wave * 32;

    __shared__ ushort Ks[2][128 * 64];
    __shared__ ushort Vs[2][64 * 128];
    __shared__ ushort Ps[4][32 * 64];

    short8 qf[2][2];
    {
        const ushort* qb = qk + ((size_t)(bb * T_ + qw)) * 2048 + head * 64;
        #pragma unroll
        for (int mt = 0; mt < 2; mt++)
            #pragma unroll
            for (int kk = 0; kk < 2; kk++)
                qf[mt][kk] = *(const short8*)(qb + (size_t)(mt*16 + lr) * 2048 + kk*32 + lq*8);
    }

    f32x4 acc[2][4];
    f32x4 lsum[2];
    float m2[2][4];
    #pragma unroll
    for (int mt = 0; mt < 2; mt++) {
        #pragma unroll
        for (int dt = 0; dt < 4; dt++) acc[mt][dt] = {0.f, 0.f, 0.f, 0.f};
        lsum[mt] = {0.f, 0.f, 0.f, 0.f};
        #pragma unroll
        for (int j = 0; j < 4; j++) m2[mt][j] = -INFINITY;
    }

    const short8 onesf = {(short)0x3F80, (short)0x3F80, (short)0x3F80, (short)0x3F80,
                          (short)0x3F80, (short)0x3F80, (short)0x3F80, (short)0x3F80};

    int krow = tid >> 3;
    int ksc = ((tid & 7) ^ (krow & 7)) * 8;
    const ushort* kg0 = qk + ((size_t)(bb * T_ + krow)) * 2048 + 1024 + head * 64 + ksc;
    int vrow = tid >> 4;
    int vsc = ((tid & 15) ^ (vrow & 7)) * 8;
    const ushort* vg0 = vt + ((size_t)(head * 64 + vrow)) * 4096 + (size_t)bb * 2048 + vsc;

    auto stage = [&](int it, int buf) {
        int s0 = it * 128;
        char* Kb = (char*)Ks[buf] + wave * 1024;
        char* Vb = (char*)Vs[buf] + wave * 1024;
        #pragma unroll
        for (int i = 0; i < 4; i++)
            GLDS16(kg0 + (size_t)(s0 + i*32) * 2048, Kb + i*4096);
        #pragma unroll
        for (int i = 0; i < 4; i++)
            GLDS16(vg0 + (size_t)(i*16) * 4096 + s0, Vb + i*4096);
    };

    int nt = qa + 1;
    stage(0, 0);
    __syncthreads();
    int cur = 0;

    for (int it = 0; it < nt; it++) {
        if (it + 1 < nt) stage(it + 1, cur ^ 1);

        const ushort* Kc = Ks[cur];
        const ushort* Vc = Vs[cur];
        #pragma unroll
        for (int h = 0; h < 2; h++) {
            int s0h = it * 128 + h * 64;
            if (s0h > qw + 31) continue;

            f32x4 sa[2][4];
            __builtin_amdgcn_s_setprio(1);
            #pragma unroll
            for (int n = 0; n < 4; n++) {
                int row = h*64 + n*16 + lr;
                const char* kbase = (const char*)Kc + row*128;
                short8 kf0 = *(const short8*)(kbase + ((lq       ^ (row & 7)) << 4));
                short8 kf1 = *(const short8*)(kbase + (((4 + lq) ^ (row & 7)) << 4));
                #pragma unroll
                for (int mt = 0; mt < 2; mt++) {
                    f32x4 tq = {0.f, 0.f, 0.f, 0.f};
                    tq = __builtin_amdgcn_mfma_f32_16x16x32_bf16(qf[mt][0], kf0, tq, 0, 0, 0);
                    tq = __builtin_amdgcn_mfma_f32_16x16x32_bf16(qf[mt][1], kf1, tq, 0, 0, 0);
                    sa[mt][n] = tq;
                }
            }
            __builtin_amdgcn_s_setprio(0);

            if (s0h + 63 > qw) {
                #pragma unroll
                for (int mt = 0; mt < 2; mt++)
                    #pragma unroll
                    for (int n = 0; n < 4; n++)
                        #pragma unroll
                        for (int j = 0; j < 4; j++) {
                            int scolm = s0h + n*16 + lr;
                            int qrow = qw + mt*16 + lq*4 + j;
                            if (scolm > qrow) sa[mt][n][j] = -INFINITY;
                        }
            }

            float vmax2[2][4];
            bool growf = false;
            #pragma unroll
            for (int mt = 0; mt < 2; mt++) {
                #pragma unroll
                for (int j = 0; j < 4; j++) {
                    float v = fmaxf(fmaxf(sa[mt][0][j], sa[mt][1][j]),
                                    fmaxf(sa[mt][2][j], sa[mt][3][j]));
                    #pragma unroll
                    for (int off = 1; off < 16; off <<= 1)
                        v = fmaxf(v, __shfl_xor(v, off));
                    float v2 = v * C2;
                    vmax2[mt][j] = v2;
                    growf |= (v2 > m2[mt][j] + THR2);
                }
            }
            if (__any(growf)) {
                #pragma unroll
                for (int mt = 0; mt < 2; mt++)
                    #pragma unroll
                    for (int j = 0; j < 4; j++) {
                        float m2n = fmaxf(m2[mt][j], vmax2[mt][j]);
                        float corr = __builtin_amdgcn_exp2f(m2[mt][j] - m2n);
                        m2[mt][j] = m2n;
                        lsum[mt][j] *= corr;
                        #pragma unroll
                        for (int dt = 0; dt < 4; dt++)
                            acc[mt][dt][j] *= corr;
                    }
            }

            char* pw = (char*)Ps[wave];
            #pragma unroll
            for (int mt = 0; mt < 2; mt++)
                #pragma unroll
                for (int n = 0; n < 4; n++)
                    #pragma unroll
                    for (int j = 0; j < 4; j++) {
                        float p = __builtin_amdgcn_exp2f(
                            fmaf(sa[mt][n][j], C2, -m2[mt][j]));
                        int row = mt*16 + lq*4 + j;
                        int col = n*16 + lr;
                        int byte = row*128 + ((((col >> 3) ^ (row & 7))) << 4) + (col & 7)*2;
                        *(ushort*)(pw + byte) = f2bf_hw(p);
                    }

            short8 pf[2][2];
            #pragma unroll
            for (int mt = 0; mt < 2; mt++) {
                int row = mt*16 + lr;
                #pragma unroll
                for (int kk = 0; kk < 2; kk++)
                    pf[mt][kk] = *(const short8*)(pw + row*128
                                   + (((kk*4 + lq) ^ (row & 7)) << 4));
            }
            __builtin_amdgcn_s_setprio(1);
            #pragma unroll
            for (int kk = 0; kk < 2; kk++)
                #pragma unroll
                for (int mt = 0; mt < 2; mt++)
                    lsum[mt] = __builtin_amdgcn_mfma_f32_16x16x32_bf16(
                        pf[mt][kk], onesf, lsum[mt], 0, 0, 0);
            #pragma unroll
            for (int dt = 0; dt < 4; dt++) {
                int row = dt*16 + lr;
                const char* vbase = (const char*)Vc + row*256;
                #pragma unroll
                for (int kk = 0; kk < 2; kk++) {
                    short8 vf = *(const short8*)(vbase
                                  + ((((h*2 + kk)*4 + lq) ^ (row & 7)) << 4));
                    #pragma unroll
                    for (int mt = 0; mt < 2; mt++)
                        acc[mt][dt] = __builtin_amdgcn_mfma_f32_16x16x32_bf16(
                            pf[mt][kk], vf, acc[mt][dt], 0, 0, 0);
                }
            }
            __builtin_amdgcn_s_setprio(0);
        }

        __syncthreads();
        cur ^= 1;
    }

    ushort* ob = attn_out + ((size_t)(bb * T_ + qw)) * 1024 + head * 64;
    #pragma unroll
    for (int mt = 0; mt < 2; mt++)
        #pragma unroll
        for (int j = 0; j < 4; j++) {
            float inv = 1.0f / lsum[mt][j];
            #pragma unroll
            for (int dt = 0; dt < 4; dt++)
                ob[(size_t)(mt*16 + lq*4 + j) * 1024 + dt*16 + lr] =
                    f2bf(acc[mt][dt][j] * inv);
        }
}

// ---------------------------------------------------------------------------
extern "C" void kernel_launch(void* const* d_in, const int* in_sizes, int n_in,
                              void* d_out, int out_size, void* d_ws, size_t ws_size,
                              hipStream_t stream) {
    const float* x   = (const float*)d_in[0];
    const float* Wq  = (const float*)d_in[1];
    const float* Wk  = (const float*)d_in[2];
    const float* Wv  = (const float*)d_in[3];
    const float* Wo  = (const float*)d_in[4];
    const float* bo  = (const float*)d_in[5];
    const float* W1  = (const float*)d_in[6];
    const float* b1  = (const float*)d_in[7];
    const float* W2  = (const float*)d_in[8];
    const float* b2  = (const float*)d_in[9];
    const float* g1  = (const float*)d_in[10];
    const float* be1 = (const float*)d_in[11];
    const float* g2  = (const float*)d_in[12];
    const float* be2 = (const float*)d_in[13];
    float* out = (float*)d_out;

    char* ws = (char*)d_ws;
    const size_t MB = 1 << 20;
    ushort* h_bf    = (ushort*)(ws);                 // 8 MB
    ushort* qk_act  = (ushort*)(ws + 8*MB);          // 16 MB [4096][2048]
    ushort* vt      = (ushort*)(ws + 24*MB);         // 8 MB  [1024][4096] V^T
    ushort* attn_bf = (ushort*)(ws + 32*MB);         // 8 MB  [4096][1024]
    ushort* ff1     = (ushort*)(ws + 8*MB);          // 32 MB (reuses qk/vt/attn)
    ushort* qkvw    = (ushort*)(ws + 40*MB);         // 6 MB  [3072][1024]
    ushort* Wo_t    = (ushort*)(ws + 46*MB);         // 2 MB
    ushort* W1_t    = (ushort*)(ws + 48*MB);         // 8 MB
    ushort* W2_t    = (ushort*)(ws + 56*MB);         // 8 MB
    ushort* p01     = (ushort*)(ws + 40*MB);         // 16 MB bf16 FF2 partials
                                                     // (reuses qkvw/Wo_t/W1_t, all dead by FF2)

    // --- weight transposes + bf16 convert ---
    const float* Wsrc[3] = {Wq, Wk, Wv};
    for (int w = 0; w < 3; w++) {
        tcvt_kernel<<<dim3(2, 32, 16), dim3(32, 8), 0, stream>>>(
            Wsrc[w], qkvw + (size_t)w * 1024 * 1024,
            1024, 64, 1024, 65536L, 65536L);
    }
    tcvt_kernel<<<dim3(32, 32, 1), dim3(32, 8), 0, stream>>>(
        Wo, Wo_t, 1024, 1024, 1024, 0L, 0L);
    tcvt_kernel<<<dim3(128, 32, 1), dim3(32, 8), 0, stream>>>(
        W1, W1_t, 1024, 4096, 1024, 0L, 0L);
    tcvt_kernel<<<dim3(32, 128, 1), dim3(32, 8), 0, stream>>>(
        W2, W2_t, 4096, 1024, 4096, 0L, 0L);

    // 1) h = LN(x) -> bf16
    ln_kernel<<<dim3(BT_), dim3(256), 0, stream>>>(x, g1, be1, h_bf);

    // 2a) qk = h @ [Wq|Wk]^T   [4096][2048]   grid 8x32 = 256 wg
    gemm2<0, true><<<dim3(2048/256, BT_/128, 1), dim3(512), 0, stream>>>(
        h_bf, qkvw, qk_act, nullptr, nullptr, BT_, 2048, C_, C_);
    // 2b) vt = Wv^T @ h^T -> V^T [1024][4096]  grid 16x8 = 128 wg
    gemm2<0, true><<<dim3(BT_/256, 1024/128, 1), dim3(512), 0, stream>>>(
        qkvw + (size_t)2*1024*1024, h_bf, vt, nullptr, nullptr, 1024, BT_, C_, C_);

    // 3) attention
    attn_mfma<<<dim3(16, B_*H_), dim3(256), 0, stream>>>(qk_act, vt, attn_bf);

    // 4) out = x + attn @ Wo + bo  (fp32)   grid 4x32 = 128 wg
    gemm2<1|4, false><<<dim3(1024/256, BT_/128, 1), dim3(512), 0, stream>>>(
        attn_bf, Wo_t, out, bo, x, BT_, C_, C_, C_);

    // 5) h2 = LN(out) -> bf16
    ln_kernel<<<dim3(BT_), dim3(256), 0, stream>>>(out, g2, be2, h_bf);

    // 6) ff1 = relu(h2 @ W1 + b1) -> bf16   grid 16x32 = 512 wg
    gemm2<1|2, true><<<dim3(FF_/256, BT_/128, 1), dim3(512), 0, stream>>>(
        h_bf, W1_t, ff1, b1, nullptr, BT_, FF_, C_, C_);

    // 7) FF2 split-K=2: partials (bf16), then out += p0 + p1 + b2
    //    grid 4x32x2 = 256 wg
    gemm2<0, true><<<dim3(1024/256, BT_/128, 2), dim3(512), 0, stream>>>(
        ff1, W2_t, p01, nullptr, nullptr, BT_, C_, FF_, 2048);
    ff2_red<<<dim3(BT_*C_/4/256), dim3(256), 0, stream>>>(out, p01, b2);
}